// Round 10
// baseline (237.637 us; speedup 1.0000x reference)
//
#include <hip/hip_runtime.h>
#include <hip/hip_cooperative_groups.h>
#include <math.h>

namespace cg = cooperative_groups;

constexpr int B = 16, T = 2048, C = 256;
constexpr int NBLK = 512, NTHR = 256;            // 2 blocks/CU * 256 CU
constexpr int NWAVE = NBLK * NTHR / 64;          // 2048 waves
constexpr int FPW = (B * T) / NWAVE;             // 16 frames/wave (pdot)
constexpr int RPW = (B * T) / NWAVE;             // 16 rows/wave (gather)

typedef float vfloat4 __attribute__((ext_vector_type(4)));

// ---------------------------------------------------------------------------
// One cooperative kernel, 4 phases separated by grid.sync():
//   1) w2:    fuse conv_w x lin_w -> w2f[3*C], bias2        (769 wave-tasks)
//   2) pdot:  P_k[bt] = dot(w2f[k], h[b,t,:])               (16 frames/wave)
//   3) scan:  blocks 0..15, per-batch prefix-sum fire logic (bit-identical to
//             the previously passing scan_kernel)
//   4) gather: out rows + zero rows + loss finalize         (16 rows/wave)
// F/A1/REM alias P0/P1/P2 (P consumed in phase 3 before overwrite; barriers
// order everything). Memory visibility across phases: grid.sync() acq/rel.
// ---------------------------------------------------------------------------
__global__ __launch_bounds__(NTHR, 2) void cif_mega(
    const float* __restrict__ h,
    const float* __restrict__ conv_w,
    const float* __restrict__ conv_b,
    const float* __restrict__ lin_w,
    const float* __restrict__ lin_b,
    float* __restrict__ ws,
    float* __restrict__ out)
{
    cg::grid_group grid = cg::this_grid();

    // workspace layout (floats)
    float* w2f   = ws;
    float* bias2 = ws + 768;
    float* alpha = ws + 1024;
    float* P0    = alpha + B * T;
    float* P1    = P0 + B * T;
    float* P2    = P1 + B * T;
    int*   F     = (int*)P0;                  // alias (post-scan)
    float* A1    = P1;                        // alias
    float* REM   = P2;                        // alias
    int*   Kaux  = (int*)(P2 + B * T);        // 2*B ints
    float* lossP = (float*)(Kaux + 2 * B);    // B floats

    int tid     = threadIdx.x;
    int bid     = blockIdx.x;
    int gthread = bid * NTHR + tid;
    int gwave   = gthread >> 6;
    int lane    = gthread & 63;               // == tid & 63

    // ---------------- phase 1: w2 ----------------
    if (gwave <= 768) {
        int wv = gwave;
        float s = 0.f;
        if (wv < 768) {
            int i = wv & 255, k = wv >> 8;    // wv = k*256 + i
#pragma unroll
            for (int m = 0; m < 4; ++m) {
                int o = lane + 64 * m;
                s = fmaf(lin_w[o], conv_w[((size_t)o * C + i) * 3 + k], s);
            }
        } else {
#pragma unroll
            for (int m = 0; m < 4; ++m) {
                int o = lane + 64 * m;
                s = fmaf(lin_w[o], conv_b[o], s);
            }
        }
#pragma unroll
        for (int off = 32; off; off >>= 1) s += __shfl_down(s, off);
        if (lane == 0) {
            if (wv < 768) w2f[wv] = s;
            else          *bias2 = s + lin_b[0];
        }
    }
    grid.sync();

    // ---------------- phase 2: pdot ----------------
    {
        int g  = lane >> 4;                   // group 0..3 (frame in chunk)
        int il = lane & 15;                   // 16 channels (4 x float4)
        const float4* w4 = (const float4*)w2f;
        float4 W0[4], W1[4], W2[4];
#pragma unroll
        for (int m = 0; m < 4; ++m) {
            W0[m] = w4[il * 4 + m];
            W1[m] = w4[64 + il * 4 + m];
            W2[m] = w4[128 + il * 4 + m];
        }
        int frame0 = gwave * FPW;
#pragma unroll
        for (int chunk = 0; chunk < FPW / 4; ++chunk) {
            int f = frame0 + chunk * 4 + g;
            const float4* hf = (const float4*)(h + (size_t)f * C);
            float s0 = 0.f, s1 = 0.f, s2 = 0.f;
#pragma unroll
            for (int m = 0; m < 4; ++m) {
                float4 hv = hf[il * 4 + m];
                s0 = fmaf(hv.x, W0[m].x, fmaf(hv.y, W0[m].y,
                     fmaf(hv.z, W0[m].z, fmaf(hv.w, W0[m].w, s0))));
                s1 = fmaf(hv.x, W1[m].x, fmaf(hv.y, W1[m].y,
                     fmaf(hv.z, W1[m].z, fmaf(hv.w, W1[m].w, s1))));
                s2 = fmaf(hv.x, W2[m].x, fmaf(hv.y, W2[m].y,
                     fmaf(hv.z, W2[m].z, fmaf(hv.w, W2[m].w, s2))));
            }
#pragma unroll
            for (int off = 8; off; off >>= 1) {
                s0 += __shfl_xor(s0, off, 16);
                s1 += __shfl_xor(s1, off, 16);
                s2 += __shfl_xor(s2, off, 16);
            }
            if (il == 0) { P0[f] = s0; P1[f] = s1; P2[f] = s2; }
        }
    }
    grid.sync();

    // ---------------- phase 3: scan (blocks 0..15) ----------------
    __shared__ float wsum[4];
    if (bid < B) {
        int b = bid;
        int wlane = tid & 63, wid = tid >> 6;
        size_t base = (size_t)b * T;
        float bias = *bias2;

        int t0 = tid * 8;
        float a[8];
        float s8 = 0.f;
#pragma unroll
        for (int j = 0; j < 8; ++j) {
            int t = t0 + j;
            size_t bt = base + t;
            float pre = P1[bt] + bias;
            if (t > 0)     pre += P0[bt - 1];
            if (t < T - 1) pre += P2[bt + 1];
            float av = 1.f / (1.f + expf(-pre));
            a[j] = av;
            s8 += av;
        }

        float x = s8;
#pragma unroll
        for (int off = 1; off < 64; off <<= 1) {
            float y = __shfl_up(x, off);
            if (wlane >= off) x += y;
        }
        if (wlane == 63) wsum[wid] = x;
        __syncthreads();                 // orders P reads before F writes
        float woff = 0.f;
#pragma unroll
        for (int w = 0; w < 4; ++w)
            if (w < wid) woff += wsum[w];
        float Sprev = woff + (x - s8);   // exclusive prefix = S_{t0-1}

        if (tid == 0)
            lossP[b] = wsum[0] + wsum[1] + wsum[2] + wsum[3];

        int*   Fb = F   + base;
        float* Ab = A1  + base;
        float* Rb = REM + base;
#pragma unroll
        for (int j = 0; j < 8; ++j) {
            int t = t0 + j;
            float S  = Sprev + a[j];
            float kp = floorf(Sprev);
            float k  = floorf(S);
            if (k > kp) {                      // integer crossing => fire
                int ji = (int)kp;
                Fb[ji] = t;
                Ab[ji] = (kp + 1.0f) - Sprev;  // a1 = TH - aa_{t-1}
                Rb[ji] = S - k;                // rem
            }
            alpha[base + t] = a[j];
            Sprev = S;
        }
        if (tid == 255) {
            float K = floorf(Sprev);
            Kaux[2 * b]     = (int)K;
            Kaux[2 * b + 1] = (Sprev - K >= 0.5f) ? 1 : 0;
        }
    }
    grid.sync();

    // ---------------- phase 4: gather ----------------
    if (gthread == 0) {
        float s = 0.f;
        for (int i = 0; i < B; ++i) s += lossP[i];
        out[(size_t)B * T * C] = s;
    }
    {
        int row0 = gwave * RPW;
        for (int rr = 0; rr < RPW; ++rr) {
            int wv = row0 + rr;
            int b = wv >> 11;
            int j = wv & (T - 1);
            int K    = Kaux[2 * b];
            int tail = Kaux[2 * b + 1];
            vfloat4* orow = (vfloat4*)(out + ((size_t)b * T + j) * C) + lane;
            if (j > K || (j == K && !tail)) {
                vfloat4 z = {0.f, 0.f, 0.f, 0.f};
                __builtin_nontemporal_store(z, orow);
                continue;
            }
            const float*  ab = alpha + (size_t)b * T;
            const float4* hb = (const float4*)(h + (size_t)b * T * C);
            const int*    Fb = F + (size_t)b * T;

            float4 acc;
            int t;
            if (j > 0) {
                int s = Fb[j - 1];
                float r = REM[(size_t)b * T + j - 1];
                float4 hv = hb[(size_t)s * 64 + lane];
                acc = make_float4(r * hv.x, r * hv.y, r * hv.z, r * hv.w);
                t = s + 1;
            } else {
                acc = make_float4(0.f, 0.f, 0.f, 0.f);
                t = 0;
            }
            int mid_end = (j == K) ? T : Fb[j];
            for (; t < mid_end; ++t) {
                float a = ab[t];
                float4 hv = hb[(size_t)t * 64 + lane];
                acc.x = fmaf(a, hv.x, acc.x);
                acc.y = fmaf(a, hv.y, acc.y);
                acc.z = fmaf(a, hv.z, acc.z);
                acc.w = fmaf(a, hv.w, acc.w);
            }
            if (j < K) {
                float a1 = A1[(size_t)b * T + j];
                float4 hv = hb[(size_t)mid_end * 64 + lane];
                acc.x = fmaf(a1, hv.x, acc.x);
                acc.y = fmaf(a1, hv.y, acc.y);
                acc.z = fmaf(a1, hv.z, acc.z);
                acc.w = fmaf(a1, hv.w, acc.w);
            }
            vfloat4 av = {acc.x, acc.y, acc.z, acc.w};
            __builtin_nontemporal_store(av, orow);
        }
    }
}

// ---------------------------------------------------------------------------
extern "C" void kernel_launch(void* const* d_in, const int* in_sizes, int n_in,
                              void* d_out, int out_size, void* d_ws, size_t ws_size,
                              hipStream_t stream) {
    const float* h      = (const float*)d_in[0];
    // d_in[1] = hs_mask (unused by the math)
    const float* conv_w = (const float*)d_in[2];
    const float* conv_b = (const float*)d_in[3];
    const float* lin_w  = (const float*)d_in[4];
    const float* lin_b  = (const float*)d_in[5];

    float* out = (float*)d_out;
    float* ws  = (float*)d_ws;

    void* args[] = {
        (void*)&h, (void*)&conv_w, (void*)&conv_b,
        (void*)&lin_w, (void*)&lin_b, (void*)&ws, (void*)&out
    };
    hipLaunchCooperativeKernel((void*)cif_mega, dim3(NBLK), dim3(NTHR),
                               args, 0, stream);
}

// Round 11
// 49.347 us; speedup vs baseline: 4.8156x; 4.8156x over previous
//
#include <hip/hip_runtime.h>
#include <math.h>

constexpr int B = 16, T = 2048, C = 256;

typedef float vfloat4 __attribute__((ext_vector_type(4)));

// ---------------------------------------------------------------------------
// Kernel 1: fuse conv_w [C_out, C_in, 3] with lin_w [C_out] -> w2f[3*C], and
// bias2 = lin_w . conv_b + lin_b. One wave per output element (769 waves).
// Also zeroes the loss slot (runs first every call -> deterministic replays).
// ---------------------------------------------------------------------------
__global__ void w2_kernel(const float* __restrict__ conv_w,
                          const float* __restrict__ conv_b,
                          const float* __restrict__ lin_w,
                          const float* __restrict__ lin_b,
                          float* __restrict__ w2f,
                          float* __restrict__ bias2,
                          float* __restrict__ out) {
    int gid  = blockIdx.x * blockDim.x + threadIdx.x;
    if (gid == 0) out[(size_t)B * T * C] = 0.f;   // loss accumulator init
    int wv   = gid >> 6;
    int lane = gid & 63;
    if (wv > 768) return;
    float s = 0.f;
    if (wv < 768) {
        int i = wv & 255, k = wv >> 8;   // wv = k*256 + i
#pragma unroll
        for (int m = 0; m < 4; ++m) {
            int o = lane + 64 * m;
            s = fmaf(lin_w[o], conv_w[((size_t)o * C + i) * 3 + k], s);
        }
    } else {
#pragma unroll
        for (int m = 0; m < 4; ++m) {
            int o = lane + 64 * m;
            s = fmaf(lin_w[o], conv_b[o], s);
        }
    }
#pragma unroll
    for (int off = 32; off; off >>= 1) s += __shfl_down(s, off);
    if (lane == 0) {
        if (wv < 768) w2f[wv] = s;
        else          *bias2 = s + lin_b[0];
    }
}

// ---------------------------------------------------------------------------
// Kernel 2: per-frame partial dots (unchanged from the passing round-9 run).
// 16-lane group owns a frame; lane covers 16 channels; FPW frames per wave.
// P_k[bt] = dot(w2f[k], h[b,t,:]); h read exactly once (32 MB).
// ---------------------------------------------------------------------------
constexpr int FPW = 8;  // frames per wave
__global__ void pdot_kernel(const float* __restrict__ h,
                            const float* __restrict__ w2f,
                            float* __restrict__ P0,
                            float* __restrict__ P1,
                            float* __restrict__ P2) {
    int gid  = blockIdx.x * blockDim.x + threadIdx.x;
    int wave = gid >> 6;
    int lane = gid & 63;
    int g    = lane >> 4;      // group 0..3 (frame within chunk)
    int il   = lane & 15;      // lane within group (16 channels)

    const float4* w4 = (const float4*)w2f;   // [3][64] float4
    float4 W0[4], W1[4], W2[4];
#pragma unroll
    for (int m = 0; m < 4; ++m) {
        W0[m] = w4[il * 4 + m];
        W1[m] = w4[64 + il * 4 + m];
        W2[m] = w4[128 + il * 4 + m];
    }

    int frame0 = wave * FPW;
#pragma unroll
    for (int chunk = 0; chunk < FPW / 4; ++chunk) {
        int f = frame0 + chunk * 4 + g;      // this group's frame
        const float4* hf = (const float4*)(h + (size_t)f * C);
        float s0 = 0.f, s1 = 0.f, s2 = 0.f;
#pragma unroll
        for (int m = 0; m < 4; ++m) {
            float4 hv = hf[il * 4 + m];
            s0 = fmaf(hv.x, W0[m].x, fmaf(hv.y, W0[m].y,
                 fmaf(hv.z, W0[m].z, fmaf(hv.w, W0[m].w, s0))));
            s1 = fmaf(hv.x, W1[m].x, fmaf(hv.y, W1[m].y,
                 fmaf(hv.z, W1[m].z, fmaf(hv.w, W1[m].w, s1))));
            s2 = fmaf(hv.x, W2[m].x, fmaf(hv.y, W2[m].y,
                 fmaf(hv.z, W2[m].z, fmaf(hv.w, W2[m].w, s2))));
        }
#pragma unroll
        for (int off = 8; off; off >>= 1) {
            s0 += __shfl_xor(s0, off, 16);
            s1 += __shfl_xor(s1, off, 16);
            s2 += __shfl_xor(s2, off, 16);
        }
        if (il == 0) { P0[f] = s0; P1[f] = s1; P2[f] = s2; }
    }
}

// ---------------------------------------------------------------------------
// Kernel 3: fused scan + gather. 2048 blocks (128/batch), 256 thr, 16 rows.
// Each block redundantly recomputes its batch's ENTIRE scan from P0/P1/P2
// (24 KB, L2-resident; bit-identical 256-thread code to the previously
// passing scan_kernel -> identical fire decisions), keeping alpha in LDS and
// capturing the 17 fire-slots [j0-1 .. j0+15] its rows need. No cross-block
// sync of any kind. Then each wave gathers 4 rows:
//   out[j] = REM[j-1]*h[s] + sum_{s<t<e} alpha[t]*h[t] + A1[j]*h[e]
// Rows past the fire count write zeros (NT stores). Per-batch block 0
// atomicAdds the batch alpha-sum into the loss slot (zeroed by w2_kernel).
// ---------------------------------------------------------------------------
constexpr int RPB = 16;   // rows per block
__global__ __launch_bounds__(256) void gather_scan(
    const float* __restrict__ h,
    const float* __restrict__ P0,
    const float* __restrict__ P1,
    const float* __restrict__ P2,
    const float* __restrict__ bias2,
    float* __restrict__ out)
{
    __shared__ float salpha[T];          // 8 KB
    __shared__ float wsum[4];
    __shared__ float sA1[RPB + 1], sREM[RPB + 1];
    __shared__ int   sF[RPB + 1];
    __shared__ int   sK, sTail;

    int tid  = threadIdx.x;              // 0..255
    int bid  = blockIdx.x;
    int b    = bid >> 7;                 // 128 blocks per batch
    int j0   = (bid & 127) * RPB;        // first row this block owns
    int lane = tid & 63, wid = tid >> 6;
    size_t base = (size_t)b * T;
    float bias = *bias2;

    // ---- scan phase 1: alpha for this thread's 8 frames ----
    int t0 = tid * 8;
    float a[8];
    float s8 = 0.f;
#pragma unroll
    for (int j = 0; j < 8; ++j) {
        int t = t0 + j;
        size_t bt = base + t;
        float pre = P1[bt] + bias;
        if (t > 0)     pre += P0[bt - 1];
        if (t < T - 1) pre += P2[bt + 1];
        float av = 1.f / (1.f + expf(-pre));
        a[j] = av;
        s8 += av;
        salpha[t] = av;
    }

    // ---- block-level exclusive scan of per-thread sums ----
    float x = s8;
#pragma unroll
    for (int off = 1; off < 64; off <<= 1) {
        float y = __shfl_up(x, off);
        if (lane >= off) x += y;
    }
    if (lane == 63) wsum[wid] = x;
    __syncthreads();
    float woff = 0.f;
#pragma unroll
    for (int w = 0; w < 4; ++w)
        if (w < wid) woff += wsum[w];
    float Sprev = woff + (x - s8);       // exclusive prefix = S_{t0-1}

    if (tid == 0 && (bid & 127) == 0)    // one block per batch adds loss
        atomicAdd(&out[(size_t)B * T * C],
                  wsum[0] + wsum[1] + wsum[2] + wsum[3]);

    // ---- fire detection; capture only slots [j0-1 .. j0+RPB-1] ----
#pragma unroll
    for (int j = 0; j < 8; ++j) {
        float S  = Sprev + a[j];
        float kp = floorf(Sprev);
        float k  = floorf(S);
        if (k > kp) {                    // integer crossing => fire at t0+j
            int ji   = (int)kp;
            int slot = ji - j0 + 1;      // slot 0 <-> fire j0-1
            if (slot >= 0 && slot <= RPB) {
                sF[slot]   = t0 + j;
                sA1[slot]  = (kp + 1.0f) - Sprev;
                sREM[slot] = S - k;
            }
        }
        Sprev = S;
    }
    if (tid == 255) {
        float K = floorf(Sprev);
        sK    = (int)K;
        sTail = (Sprev - K >= 0.5f) ? 1 : 0;
    }
    __syncthreads();

    // ---- gather: wave w handles rows j0+4w .. j0+4w+3 ----
    int K = sK, tail = sTail;
    const float4* hb = (const float4*)(h + base * C);
#pragma unroll
    for (int r = 0; r < 4; ++r) {
        int j = j0 + wid * 4 + r;
        vfloat4* orow = (vfloat4*)(out + (base + j) * C) + lane;
        if (j > K || (j == K && !tail)) {
            vfloat4 z = {0.f, 0.f, 0.f, 0.f};
            __builtin_nontemporal_store(z, orow);
            continue;
        }
        float4 acc;
        int t;
        if (j > 0) {
            int s   = sF[j - j0];        // F[j-1]
            float rr = sREM[j - j0];     // REM[j-1]
            float4 hv = hb[(size_t)s * 64 + lane];
            acc = make_float4(rr * hv.x, rr * hv.y, rr * hv.z, rr * hv.w);
            t = s + 1;
        } else {
            acc = make_float4(0.f, 0.f, 0.f, 0.f);
            t = 0;
        }
        int mid_end = (j == K) ? T : sF[j - j0 + 1];
        for (; t < mid_end; ++t) {
            float av = salpha[t];
            float4 hv = hb[(size_t)t * 64 + lane];
            acc.x = fmaf(av, hv.x, acc.x);
            acc.y = fmaf(av, hv.y, acc.y);
            acc.z = fmaf(av, hv.z, acc.z);
            acc.w = fmaf(av, hv.w, acc.w);
        }
        if (j < K) {
            float a1 = sA1[j - j0 + 1];
            float4 hv = hb[(size_t)mid_end * 64 + lane];
            acc.x = fmaf(a1, hv.x, acc.x);
            acc.y = fmaf(a1, hv.y, acc.y);
            acc.z = fmaf(a1, hv.z, acc.z);
            acc.w = fmaf(a1, hv.w, acc.w);
        }
        vfloat4 av4 = {acc.x, acc.y, acc.z, acc.w};
        __builtin_nontemporal_store(av4, orow);
    }
}

// ---------------------------------------------------------------------------
extern "C" void kernel_launch(void* const* d_in, const int* in_sizes, int n_in,
                              void* d_out, int out_size, void* d_ws, size_t ws_size,
                              hipStream_t stream) {
    const float* h      = (const float*)d_in[0];
    // d_in[1] = hs_mask (unused by the math)
    const float* conv_w = (const float*)d_in[2];
    const float* conv_b = (const float*)d_in[3];
    const float* lin_w  = (const float*)d_in[4];
    const float* lin_b  = (const float*)d_in[5];

    float* out = (float*)d_out;

    // workspace layout (floats): w2f[768] | bias2 (pad to 1024) | P0 | P1 | P2
    float* w2f   = (float*)d_ws;
    float* bias2 = w2f + 768;
    float* P0    = w2f + 1024;
    float* P1    = P0 + B * T;
    float* P2    = P1 + B * T;

    hipLaunchKernelGGL(w2_kernel, dim3(193), dim3(256), 0, stream,
                       conv_w, conv_b, lin_w, lin_b, w2f, bias2, out);

    hipLaunchKernelGGL(pdot_kernel, dim3(B * T / (4 * FPW)), dim3(256), 0, stream,
                       h, w2f, P0, P1, P2);

    hipLaunchKernelGGL(gather_scan, dim3(B * T / RPB), dim3(256), 0, stream,
                       h, P0, P1, P2, bias2, out);
}

// Round 12
// 44.774 us; speedup vs baseline: 5.3075x; 1.1021x over previous
//
#include <hip/hip_runtime.h>
#include <math.h>

constexpr int B = 16, T = 2048, C = 256;

typedef float vfloat4 __attribute__((ext_vector_type(4)));

// ---------------------------------------------------------------------------
// Kernel 1: fuse conv_w [C_out, C_in, 3] with lin_w [C_out] -> w2f[3*C], and
// bias2 = lin_w . conv_b + lin_b.  COALESCED: thread e owns fused element
// e = i*3+k and loops o; conv_w[o*768 + e] is contiguous across threads, so
// the 768 KB weight tensor is read exactly once, coalesced (vs the previous
// lane-per-o layout: ~196K scattered stride-3KB requests).
// Blocks 0..11 (64 thr): w2f. Block 12: bias2 via wave reduction.
// w2f layout [k][i]: preact(t) = sum_i w2f[0][i]*h[t-1,i] + w2f[1][i]*h[t,i]
//                              + w2f[2][i]*h[t+1,i] + bias2
// ---------------------------------------------------------------------------
__global__ void w2_kernel(const float* __restrict__ conv_w,
                          const float* __restrict__ conv_b,
                          const float* __restrict__ lin_w,
                          const float* __restrict__ lin_b,
                          float* __restrict__ w2f,
                          float* __restrict__ bias2) {
    int bid  = blockIdx.x;
    int lane = threadIdx.x;          // 0..63
    if (bid < 12) {
        int e = bid * 64 + lane;     // 0..767, e = i*3 + k
        float s = 0.f;
#pragma unroll 8
        for (int o = 0; o < 256; ++o)
            s = fmaf(lin_w[o], conv_w[(size_t)o * 768 + e], s);
        w2f[(e % 3) * C + (e / 3)] = s;
    } else {
        float s = 0.f;
#pragma unroll
        for (int m = 0; m < 4; ++m) {
            int o = lane + 64 * m;
            s = fmaf(lin_w[o], conv_b[o], s);
        }
#pragma unroll
        for (int off = 32; off; off >>= 1) s += __shfl_down(s, off);
        if (lane == 0) *bias2 = s + lin_b[0];
    }
}

// ---------------------------------------------------------------------------
// Kernel 2: per-frame partial dots (unchanged from the passing round-9 run).
// 16-lane group owns a frame; lane covers 16 channels; FPW frames per wave.
// P_k[bt] = dot(w2f[k], h[b,t,:]); h read exactly once (32 MB).
// ---------------------------------------------------------------------------
constexpr int FPW = 8;  // frames per wave
__global__ void pdot_kernel(const float* __restrict__ h,
                            const float* __restrict__ w2f,
                            float* __restrict__ P0,
                            float* __restrict__ P1,
                            float* __restrict__ P2) {
    int gid  = blockIdx.x * blockDim.x + threadIdx.x;
    int wave = gid >> 6;
    int lane = gid & 63;
    int g    = lane >> 4;      // group 0..3 (frame within chunk)
    int il   = lane & 15;      // lane within group (16 channels)

    const float4* w4 = (const float4*)w2f;   // [3][64] float4
    float4 W0[4], W1[4], W2[4];
#pragma unroll
    for (int m = 0; m < 4; ++m) {
        W0[m] = w4[il * 4 + m];
        W1[m] = w4[64 + il * 4 + m];
        W2[m] = w4[128 + il * 4 + m];
    }

    int frame0 = wave * FPW;
#pragma unroll
    for (int chunk = 0; chunk < FPW / 4; ++chunk) {
        int f = frame0 + chunk * 4 + g;      // this group's frame
        const float4* hf = (const float4*)(h + (size_t)f * C);
        float s0 = 0.f, s1 = 0.f, s2 = 0.f;
#pragma unroll
        for (int m = 0; m < 4; ++m) {
            float4 hv = hf[il * 4 + m];
            s0 = fmaf(hv.x, W0[m].x, fmaf(hv.y, W0[m].y,
                 fmaf(hv.z, W0[m].z, fmaf(hv.w, W0[m].w, s0))));
            s1 = fmaf(hv.x, W1[m].x, fmaf(hv.y, W1[m].y,
                 fmaf(hv.z, W1[m].z, fmaf(hv.w, W1[m].w, s1))));
            s2 = fmaf(hv.x, W2[m].x, fmaf(hv.y, W2[m].y,
                 fmaf(hv.z, W2[m].z, fmaf(hv.w, W2[m].w, s2))));
        }
#pragma unroll
        for (int off = 8; off; off >>= 1) {
            s0 += __shfl_xor(s0, off, 16);
            s1 += __shfl_xor(s1, off, 16);
            s2 += __shfl_xor(s2, off, 16);
        }
        if (il == 0) { P0[f] = s0; P1[f] = s1; P2[f] = s2; }
    }
}

// ---------------------------------------------------------------------------
// Kernel 3: fused alpha + loss partial + parallel fire computation via prefix
// sum (unchanged from the passing round-9 run). One block per batch row.
//   aa_t == S_t - floor(S_t), fire at t <=> floor(S_t) > floor(S_{t-1}),
//   j = floor(S_{t-1}), a1 = (j+1)-S_{t-1}, rem = S_t-floor(S_t),
//   K = floor(S_{T-1}), tail = frac >= 0.5.
// F/A1/REM alias P0/P1/P2: all P reads precede the __syncthreads(), all
// F/A1/REM writes follow it; each block touches only its own batch range.
// ---------------------------------------------------------------------------
__global__ void scan_kernel(const float* __restrict__ P0,
                            const float* __restrict__ P1,
                            const float* __restrict__ P2,
                            const float* __restrict__ bias2,
                            float* __restrict__ alpha,
                            int*   __restrict__ F,
                            float* __restrict__ A1,
                            float* __restrict__ REM,
                            int*   __restrict__ Kaux,
                            float* __restrict__ lossP) {
    __shared__ float wsum[4];
    int b    = blockIdx.x;
    int tid  = threadIdx.x;        // 0..255
    int lane = tid & 63, wid = tid >> 6;
    size_t base = (size_t)b * T;
    float bias = *bias2;

    int t0 = tid * 8;
    float a[8];
    float s8 = 0.f;
#pragma unroll
    for (int j = 0; j < 8; ++j) {
        int t = t0 + j;
        size_t bt = base + t;
        float pre = P1[bt] + bias;
        if (t > 0)     pre += P0[bt - 1];
        if (t < T - 1) pre += P2[bt + 1];
        float av = 1.f / (1.f + expf(-pre));
        a[j] = av;
        s8 += av;
    }

    float x = s8;
#pragma unroll
    for (int off = 1; off < 64; off <<= 1) {
        float y = __shfl_up(x, off);
        if (lane >= off) x += y;
    }
    if (lane == 63) wsum[wid] = x;
    __syncthreads();                       // orders P reads before F writes
    float woff = 0.f;
#pragma unroll
    for (int w = 0; w < 4; ++w)
        if (w < wid) woff += wsum[w];
    float Sprev = woff + (x - s8);         // exclusive prefix = S_{t0-1}

    if (tid == 0)
        lossP[b] = wsum[0] + wsum[1] + wsum[2] + wsum[3];

    int*   Fb = F   + base;
    float* Ab = A1  + base;
    float* Rb = REM + base;
#pragma unroll
    for (int j = 0; j < 8; ++j) {
        int t = t0 + j;
        float S  = Sprev + a[j];
        float kp = floorf(Sprev);
        float k  = floorf(S);
        if (k > kp) {                      // integer crossing => fire at t
            int ji = (int)kp;
            Fb[ji] = t;
            Ab[ji] = (kp + 1.0f) - Sprev;  // a1 = TH - aa_{t-1}
            Rb[ji] = S - k;                // rem carried into next cell
        }
        alpha[base + t] = a[j];
        Sprev = S;
    }
    if (tid == 255) {
        float K = floorf(Sprev);
        Kaux[2 * b]     = (int)K;
        Kaux[2 * b + 1] = (Sprev - K >= 0.5f) ? 1 : 0;
    }
}

// ---------------------------------------------------------------------------
// Kernel 4: gather (unchanged from the passing round-9 run). One wave per
// output row; lane owns 4 channels; ascending-t accumulation; zero rows via
// NT stores; thread 0 finalizes loss from lossP.
// ---------------------------------------------------------------------------
__global__ void gather_kernel(const float* __restrict__ h,
                              const float* __restrict__ alpha,
                              const int*   __restrict__ F,
                              const float* __restrict__ A1,
                              const float* __restrict__ REM,
                              const int*   __restrict__ Kaux,
                              const float* __restrict__ lossP,
                              float* __restrict__ out) {
    int gid  = blockIdx.x * blockDim.x + threadIdx.x;
    int wv   = gid >> 6;
    int lane = gid & 63;
    if (gid == 0) {
        float s = 0.f;
        for (int i = 0; i < B; ++i) s += lossP[i];
        out[(size_t)B * T * C] = s;
    }
    if (wv >= B * T) return;
    int b = wv >> 11;
    int j = wv & (T - 1);
    int K    = Kaux[2 * b];
    int tail = Kaux[2 * b + 1];
    vfloat4* orow = (vfloat4*)(out + ((size_t)b * T + j) * C) + lane;
    if (j > K || (j == K && !tail)) {
        vfloat4 z = {0.f, 0.f, 0.f, 0.f};
        __builtin_nontemporal_store(z, orow);
        return;
    }
    const float*  ab = alpha + (size_t)b * T;
    const float4* hb = (const float4*)(h + (size_t)b * T * C);
    const int*    Fb = F + (size_t)b * T;

    float4 acc;
    int t;
    if (j > 0) {
        int s = Fb[j - 1];
        float r = REM[(size_t)b * T + j - 1];
        float4 hv = hb[(size_t)s * 64 + lane];
        acc = make_float4(r * hv.x, r * hv.y, r * hv.z, r * hv.w);
        t = s + 1;
    } else {
        acc = make_float4(0.f, 0.f, 0.f, 0.f);
        t = 0;
    }
    int mid_end = (j == K) ? T : Fb[j];
    for (; t < mid_end; ++t) {
        float a = ab[t];
        float4 hv = hb[(size_t)t * 64 + lane];
        acc.x = fmaf(a, hv.x, acc.x);
        acc.y = fmaf(a, hv.y, acc.y);
        acc.z = fmaf(a, hv.z, acc.z);
        acc.w = fmaf(a, hv.w, acc.w);
    }
    if (j < K) {
        float a1 = A1[(size_t)b * T + j];
        float4 hv = hb[(size_t)mid_end * 64 + lane];
        acc.x = fmaf(a1, hv.x, acc.x);
        acc.y = fmaf(a1, hv.y, acc.y);
        acc.z = fmaf(a1, hv.z, acc.z);
        acc.w = fmaf(a1, hv.w, acc.w);
    }
    vfloat4 av = {acc.x, acc.y, acc.z, acc.w};
    __builtin_nontemporal_store(av, orow);
}

// ---------------------------------------------------------------------------
extern "C" void kernel_launch(void* const* d_in, const int* in_sizes, int n_in,
                              void* d_out, int out_size, void* d_ws, size_t ws_size,
                              hipStream_t stream) {
    const float* h      = (const float*)d_in[0];
    // d_in[1] = hs_mask (unused by the math)
    const float* conv_w = (const float*)d_in[2];
    const float* conv_b = (const float*)d_in[3];
    const float* lin_w  = (const float*)d_in[4];
    const float* lin_b  = (const float*)d_in[5];

    float* out = (float*)d_out;

    // workspace layout (floats):
    //   w2f[768] | bias2 (pad to 1024) | alpha[B*T] | P0[B*T] | P1[B*T]
    //   | P2[B*T] | Kaux[2B ints] | lossP[B]
    // F/A1/REM alias P0/P1/P2 (safe: see scan_kernel comment).
    float* w2f   = (float*)d_ws;
    float* bias2 = w2f + 768;
    float* alpha = w2f + 1024;
    float* P0    = alpha + B * T;
    float* P1    = P0 + B * T;
    float* P2    = P1 + B * T;
    int*   F     = (int*)P0;
    float* A1    = P1;
    float* REM   = P2;
    int*   Kaux  = (int*)(P2 + B * T);        // 2*B ints
    float* lossP = (float*)(Kaux + 2 * B);    // B floats

    hipLaunchKernelGGL(w2_kernel, dim3(13), dim3(64), 0, stream,
                       conv_w, conv_b, lin_w, lin_b, w2f, bias2);

    hipLaunchKernelGGL(pdot_kernel, dim3(B * T / (4 * FPW)), dim3(256), 0, stream,
                       h, w2f, P0, P1, P2);

    hipLaunchKernelGGL(scan_kernel, dim3(B), dim3(256), 0, stream,
                       P0, P1, P2, bias2, alpha, F, A1, REM, Kaux, lossP);

    hipLaunchKernelGGL(gather_kernel, dim3(B * T / 4), dim3(256), 0, stream,
                       h, alpha, F, A1, REM, Kaux, lossP, out);
}

// Round 13
// 36.709 us; speedup vs baseline: 6.4735x; 1.2197x over previous
//
#include <hip/hip_runtime.h>
#include <math.h>

constexpr int B = 16, T = 2048, C = 256;

typedef float vfloat4 __attribute__((ext_vector_type(4)));

// ---------------------------------------------------------------------------
// Kernel 1: fuse conv_w [C_out, C_in, 3] with lin_w [C_out] -> w2f[3*C], and
// bias2 = lin_w . conv_b + lin_b. One wave per output element (769 waves).
// NOTE (r12 post-mortem): a "coalesced" 13-wave variant was 8 us SLOWER —
// 772 waves of latency hiding over the L2-resident 786 KB tensor beats
// coalescing. Keep this layout.
// w2f layout [k][i]: preact(t) = sum_i w2f[0][i]*h[t-1,i] + w2f[1][i]*h[t,i]
//                              + w2f[2][i]*h[t+1,i] + bias2
// ---------------------------------------------------------------------------
__global__ void w2_kernel(const float* __restrict__ conv_w,
                          const float* __restrict__ conv_b,
                          const float* __restrict__ lin_w,
                          const float* __restrict__ lin_b,
                          float* __restrict__ w2f,
                          float* __restrict__ bias2) {
    int gid  = blockIdx.x * blockDim.x + threadIdx.x;
    int wv   = gid >> 6;
    int lane = gid & 63;
    if (wv > 768) return;
    float s = 0.f;
    if (wv < 768) {
        int i = wv & 255, k = wv >> 8;   // wv = k*256 + i
#pragma unroll
        for (int m = 0; m < 4; ++m) {
            int o = lane + 64 * m;
            s = fmaf(lin_w[o], conv_w[((size_t)o * C + i) * 3 + k], s);
        }
    } else {
#pragma unroll
        for (int m = 0; m < 4; ++m) {
            int o = lane + 64 * m;
            s = fmaf(lin_w[o], conv_b[o], s);
        }
    }
#pragma unroll
    for (int off = 32; off; off >>= 1) s += __shfl_down(s, off);
    if (lane == 0) {
        if (wv < 768) w2f[wv] = s;
        else          *bias2 = s + lin_b[0];
    }
}

// ---------------------------------------------------------------------------
// Kernel 2: per-frame partial dots. 16-lane group owns a frame; lane covers
// 16 channels (4 x float4); weights hoisted to registers; FPW frames/wave.
// P_k[bt] = dot(w2f[k], h[b,t,:]); h read exactly once (32 MB).
// ---------------------------------------------------------------------------
constexpr int FPW = 8;  // frames per wave
__global__ void pdot_kernel(const float* __restrict__ h,
                            const float* __restrict__ w2f,
                            float* __restrict__ P0,
                            float* __restrict__ P1,
                            float* __restrict__ P2) {
    int gid  = blockIdx.x * blockDim.x + threadIdx.x;
    int wave = gid >> 6;
    int lane = gid & 63;
    int g    = lane >> 4;      // group 0..3 (frame within chunk)
    int il   = lane & 15;      // lane within group (16 channels)

    const float4* w4 = (const float4*)w2f;   // [3][64] float4
    float4 W0[4], W1[4], W2[4];
#pragma unroll
    for (int m = 0; m < 4; ++m) {
        W0[m] = w4[il * 4 + m];
        W1[m] = w4[64 + il * 4 + m];
        W2[m] = w4[128 + il * 4 + m];
    }

    int frame0 = wave * FPW;
#pragma unroll
    for (int chunk = 0; chunk < FPW / 4; ++chunk) {
        int f = frame0 + chunk * 4 + g;      // this group's frame
        const float4* hf = (const float4*)(h + (size_t)f * C);
        float s0 = 0.f, s1 = 0.f, s2 = 0.f;
#pragma unroll
        for (int m = 0; m < 4; ++m) {
            float4 hv = hf[il * 4 + m];
            s0 = fmaf(hv.x, W0[m].x, fmaf(hv.y, W0[m].y,
                 fmaf(hv.z, W0[m].z, fmaf(hv.w, W0[m].w, s0))));
            s1 = fmaf(hv.x, W1[m].x, fmaf(hv.y, W1[m].y,
                 fmaf(hv.z, W1[m].z, fmaf(hv.w, W1[m].w, s1))));
            s2 = fmaf(hv.x, W2[m].x, fmaf(hv.y, W2[m].y,
                 fmaf(hv.z, W2[m].z, fmaf(hv.w, W2[m].w, s2))));
        }
#pragma unroll
        for (int off = 8; off; off >>= 1) {
            s0 += __shfl_xor(s0, off, 16);
            s1 += __shfl_xor(s1, off, 16);
            s2 += __shfl_xor(s2, off, 16);
        }
        if (il == 0) { P0[f] = s0; P1[f] = s1; P2[f] = s2; }
    }
}

// ---------------------------------------------------------------------------
// Kernel 3: fused alpha + loss partial + parallel fire computation via prefix
// sum. One block (256 threads) per batch row; 8 frames per thread.
//   aa_t == S_t - floor(S_t), fire at t <=> floor(S_t) > floor(S_{t-1}),
//   j = floor(S_{t-1}), a1 = (j+1)-S_{t-1}, rem = S_t-floor(S_t),
//   K = floor(S_{T-1}), tail = frac >= 0.5.
// F/A1/REM alias P0/P1/P2: all P reads precede the __syncthreads(), all
// F/A1/REM writes follow it; each block touches only its own batch range.
// ---------------------------------------------------------------------------
__global__ void scan_kernel(const float* __restrict__ P0,
                            const float* __restrict__ P1,
                            const float* __restrict__ P2,
                            const float* __restrict__ bias2,
                            float* __restrict__ alpha,
                            int*   __restrict__ F,
                            float* __restrict__ A1,
                            float* __restrict__ REM,
                            int*   __restrict__ Kaux,
                            float* __restrict__ lossP) {
    __shared__ float wsum[4];
    int b    = blockIdx.x;
    int tid  = threadIdx.x;        // 0..255
    int lane = tid & 63, wid = tid >> 6;
    size_t base = (size_t)b * T;
    float bias = *bias2;

    int t0 = tid * 8;
    float a[8];
    float s8 = 0.f;
#pragma unroll
    for (int j = 0; j < 8; ++j) {
        int t = t0 + j;
        size_t bt = base + t;
        float pre = P1[bt] + bias;
        if (t > 0)     pre += P0[bt - 1];
        if (t < T - 1) pre += P2[bt + 1];
        float av = 1.f / (1.f + expf(-pre));
        a[j] = av;
        s8 += av;
    }

    float x = s8;
#pragma unroll
    for (int off = 1; off < 64; off <<= 1) {
        float y = __shfl_up(x, off);
        if (lane >= off) x += y;
    }
    if (lane == 63) wsum[wid] = x;
    __syncthreads();                       // orders P reads before F writes
    float woff = 0.f;
#pragma unroll
    for (int w = 0; w < 4; ++w)
        if (w < wid) woff += wsum[w];
    float Sprev = woff + (x - s8);         // exclusive prefix = S_{t0-1}

    if (tid == 0)
        lossP[b] = wsum[0] + wsum[1] + wsum[2] + wsum[3];

    int*   Fb = F   + base;
    float* Ab = A1  + base;
    float* Rb = REM + base;
#pragma unroll
    for (int j = 0; j < 8; ++j) {
        int t = t0 + j;
        float S  = Sprev + a[j];
        float kp = floorf(Sprev);
        float k  = floorf(S);
        if (k > kp) {                      // integer crossing => fire at t
            int ji = (int)kp;
            Fb[ji] = t;
            Ab[ji] = (kp + 1.0f) - Sprev;  // a1 = TH - aa_{t-1}
            Rb[ji] = S - k;                // rem carried into next cell
        }
        alpha[base + t] = a[j];
        Sprev = S;
    }
    if (tid == 255) {
        float K = floorf(Sprev);
        Kaux[2 * b]     = (int)K;
        Kaux[2 * b + 1] = (Sprev - K >= 0.5f) ? 1 : 0;
    }
}

// ---------------------------------------------------------------------------
// Kernel 4: gather. One wave per output row (b, j); lane owns 4 channels.
// out[j] = REM[j-1]*h[s] + sum_{s<t<e} alpha[t]*h[t] + A1[j]*h[e],
// ascending-t accumulation (matches reference hacc order). Rows past the
// fire count write zeros (NT stores keep the 33.5 MB stream from evicting h
// in L2). Thread 0 finalizes loss from lossP.
// ---------------------------------------------------------------------------
__global__ void gather_kernel(const float* __restrict__ h,
                              const float* __restrict__ alpha,
                              const int*   __restrict__ F,
                              const float* __restrict__ A1,
                              const float* __restrict__ REM,
                              const int*   __restrict__ Kaux,
                              const float* __restrict__ lossP,
                              float* __restrict__ out) {
    int gid  = blockIdx.x * blockDim.x + threadIdx.x;
    int wv   = gid >> 6;
    int lane = gid & 63;
    if (gid == 0) {
        float s = 0.f;
        for (int i = 0; i < B; ++i) s += lossP[i];
        out[(size_t)B * T * C] = s;
    }
    if (wv >= B * T) return;
    int b = wv >> 11;
    int j = wv & (T - 1);
    int K    = Kaux[2 * b];
    int tail = Kaux[2 * b + 1];
    vfloat4* orow = (vfloat4*)(out + ((size_t)b * T + j) * C) + lane;
    if (j > K || (j == K && !tail)) {
        vfloat4 z = {0.f, 0.f, 0.f, 0.f};
        __builtin_nontemporal_store(z, orow);
        return;
    }
    const float*  ab = alpha + (size_t)b * T;
    const float4* hb = (const float4*)(h + (size_t)b * T * C);
    const int*    Fb = F + (size_t)b * T;

    float4 acc;
    int t;
    if (j > 0) {
        int s = Fb[j - 1];
        float r = REM[(size_t)b * T + j - 1];
        float4 hv = hb[(size_t)s * 64 + lane];
        acc = make_float4(r * hv.x, r * hv.y, r * hv.z, r * hv.w);
        t = s + 1;
    } else {
        acc = make_float4(0.f, 0.f, 0.f, 0.f);
        t = 0;
    }
    int mid_end = (j == K) ? T : Fb[j];
    for (; t < mid_end; ++t) {
        float a = ab[t];
        float4 hv = hb[(size_t)t * 64 + lane];
        acc.x = fmaf(a, hv.x, acc.x);
        acc.y = fmaf(a, hv.y, acc.y);
        acc.z = fmaf(a, hv.z, acc.z);
        acc.w = fmaf(a, hv.w, acc.w);
    }
    if (j < K) {
        float a1 = A1[(size_t)b * T + j];
        float4 hv = hb[(size_t)mid_end * 64 + lane];
        acc.x = fmaf(a1, hv.x, acc.x);
        acc.y = fmaf(a1, hv.y, acc.y);
        acc.z = fmaf(a1, hv.z, acc.z);
        acc.w = fmaf(a1, hv.w, acc.w);
    }
    vfloat4 av = {acc.x, acc.y, acc.z, acc.w};
    __builtin_nontemporal_store(av, orow);
}

// ---------------------------------------------------------------------------
extern "C" void kernel_launch(void* const* d_in, const int* in_sizes, int n_in,
                              void* d_out, int out_size, void* d_ws, size_t ws_size,
                              hipStream_t stream) {
    const float* h      = (const float*)d_in[0];
    // d_in[1] = hs_mask (unused by the math)
    const float* conv_w = (const float*)d_in[2];
    const float* conv_b = (const float*)d_in[3];
    const float* lin_w  = (const float*)d_in[4];
    const float* lin_b  = (const float*)d_in[5];

    float* out = (float*)d_out;

    // workspace layout (floats):
    //   w2f[768] | bias2 (pad to 1024) | alpha[B*T] | P0[B*T] | P1[B*T]
    //   | P2[B*T] | Kaux[2B ints] | lossP[B]
    // F/A1/REM alias P0/P1/P2 (safe: see scan_kernel comment).
    float* w2f   = (float*)d_ws;
    float* bias2 = w2f + 768;
    float* alpha = w2f + 1024;
    float* P0    = alpha + B * T;
    float* P1    = P0 + B * T;
    float* P2    = P1 + B * T;
    int*   F     = (int*)P0;
    float* A1    = P1;
    float* REM   = P2;
    int*   Kaux  = (int*)(P2 + B * T);        // 2*B ints
    float* lossP = (float*)(Kaux + 2 * B);    // B floats

    hipLaunchKernelGGL(w2_kernel, dim3(193), dim3(256), 0, stream,
                       conv_w, conv_b, lin_w, lin_b, w2f, bias2);

    hipLaunchKernelGGL(pdot_kernel, dim3(B * T / (4 * FPW)), dim3(256), 0, stream,
                       h, w2f, P0, P1, P2);

    hipLaunchKernelGGL(scan_kernel, dim3(B), dim3(256), 0, stream,
                       P0, P1, P2, bias2, alpha, F, A1, REM, Kaux, lossP);

    hipLaunchKernelGGL(gather_kernel, dim3(B * T / 4), dim3(256), 0, stream,
                       h, alpha, F, A1, REM, Kaux, lossP, out);
}